// Round 1
// baseline (303.846 us; speedup 1.0000x reference)
//
#include <hip/hip_runtime.h>

// DynamicConv: LN -> GEMM+GLU -> GEMM+softmax(K=31) -> depthwise dynamic conv + residual
// B=8, T=2048, C=1024, H=16, hd=64, K=31.  All heavy GEMMs in bf16 MFMA.

typedef __bf16 bf16_t;
typedef __attribute__((ext_vector_type(8))) __bf16 bf16x8;
typedef __attribute__((ext_vector_type(4))) __bf16 bf16x4;
typedef __attribute__((ext_vector_type(4))) float f32x4;

__device__ __forceinline__ void gload_lds16(const void* g, void* l) {
  void* gg = const_cast<void*>(g);
  __builtin_amdgcn_global_load_lds(
      (__attribute__((address_space(1))) unsigned int*)gg,
      (__attribute__((address_space(3))) unsigned int*)l, 16, 0, 0);
}

// ---------- weight prep: transpose to [N][K] bf16 ----------
// WT1[c][k] = Wk[k][src(c)], src interleaves a/gate columns so GLU pairs are adjacent.
__global__ __launch_bounds__(256) void prep_wk(const float* __restrict__ Wk,
                                               bf16_t* __restrict__ WT) {
  int c = blockIdx.x;                       // [0,2048)
  int s = (c & 1) ? 1024 + (c >> 1) : (c >> 1);
  int k = threadIdx.x * 4;
  bf16x4 v;
#pragma unroll
  for (int j = 0; j < 4; ++j) v[j] = (bf16_t)Wk[(size_t)(k + j) * 2048 + s];
  *(bf16x4*)&WT[(size_t)c * 1024 + k] = v;
}

// WT2[n][k] = Wck[k][n] for n<496 else 0 (pad N to 512)
__global__ __launch_bounds__(256) void prep_wck(const float* __restrict__ Wck,
                                                bf16_t* __restrict__ WT) {
  int n = blockIdx.x;                       // [0,512)
  int k = threadIdx.x * 4;
  bf16x4 v;
#pragma unroll
  for (int j = 0; j < 4; ++j)
    v[j] = (n < 496) ? (bf16_t)Wck[(size_t)(k + j) * 496 + n] : (bf16_t)(0.f);
  *(bf16x4*)&WT[(size_t)n * 1024 + k] = v;
}

// ---------- layernorm: x[row][1024] -> h bf16 ----------
__global__ __launch_bounds__(256) void ln_kernel(const float* __restrict__ x,
                                                 const float* __restrict__ gamma,
                                                 const float* __restrict__ beta,
                                                 bf16_t* __restrict__ h) {
  int row = blockIdx.x;
  int tid = threadIdx.x;
  int lane = tid & 63, wid = tid >> 6;
  const float4* xr = (const float4*)(x + (size_t)row * 1024);
  float4 v = xr[tid];
  __shared__ float red[4];
  __shared__ float bc[2];
  float s = v.x + v.y + v.z + v.w;
#pragma unroll
  for (int off = 32; off > 0; off >>= 1) s += __shfl_down(s, off);
  if (lane == 0) red[wid] = s;
  __syncthreads();
  if (tid == 0) bc[0] = (red[0] + red[1] + red[2] + red[3]) * (1.f / 1024.f);
  __syncthreads();
  float mu = bc[0];
  float dx = v.x - mu, dy = v.y - mu, dz = v.z - mu, dw = v.w - mu;
  float s2 = dx * dx + dy * dy + dz * dz + dw * dw;
#pragma unroll
  for (int off = 32; off > 0; off >>= 1) s2 += __shfl_down(s2, off);
  if (lane == 0) red[wid] = s2;
  __syncthreads();
  if (tid == 0)
    bc[1] = rsqrtf((red[0] + red[1] + red[2] + red[3]) * (1.f / 1024.f) + 1e-5f);
  __syncthreads();
  float rs = bc[1];
  const float4* g4 = (const float4*)gamma;
  const float4* b4 = (const float4*)beta;
  float4 gv = g4[tid], bv = b4[tid];
  bf16x4 o;
  o[0] = (bf16_t)(dx * rs * gv.x + bv.x);
  o[1] = (bf16_t)(dy * rs * gv.y + bv.y);
  o[2] = (bf16_t)(dz * rs * gv.z + bv.z);
  o[3] = (bf16_t)(dw * rs * gv.w + bv.w);
  *(bf16x4*)&h[(size_t)row * 1024 + tid * 4] = o;
}

// ---------- 128x128 tile GEMM (m97 structure), K=1024, BK=32 ----------
// EPI=0: GLU epilogue -> bf16 k  [M][1024]  (N=2048 interleaved a/g)
// EPI=1: bias epilogue -> f32 logits [M][512]
template <int EPI>
__global__ __launch_bounds__(256, 2) void gemm128(const bf16_t* __restrict__ Ag,
                                                  const bf16_t* __restrict__ Bg,
                                                  const float* __restrict__ bias,
                                                  void* __restrict__ outp) {
  __shared__ bf16_t As[2][128 * 32];
  __shared__ bf16_t Bs[2][128 * 32];
  int tid = threadIdx.x;
  int lane = tid & 63;
  int wid = tid >> 6;
  int wr = wid >> 1, wc = wid & 1;
  int n0 = blockIdx.x * 128;
  int m0 = blockIdx.y * 128;

  f32x4 acc[4][4] = {};

#define STAGE(bufi, kt)                                                         \
  {                                                                             \
    _Pragma("unroll") for (int s_ = 0; s_ < 2; ++s_) {                          \
      int idx = (tid + s_ * 256) * 8;                                           \
      int row = idx >> 5;                                                       \
      int col = idx & 31;                                                       \
      gload_lds16(Ag + (size_t)(m0 + row) * 1024 + (kt) + col, &As[bufi][idx]); \
      gload_lds16(Bg + (size_t)(n0 + row) * 1024 + (kt) + col, &Bs[bufi][idx]); \
    }                                                                           \
  }

#define COMPUTE(bufi)                                                           \
  {                                                                             \
    int ko = (lane >> 4) * 8;                                                   \
    int rl = lane & 15;                                                         \
    bf16x8 af[4], bb[4];                                                        \
    _Pragma("unroll") for (int m_ = 0; m_ < 4; ++m_)                            \
        af[m_] = *(const bf16x8*)&As[bufi][(wr * 64 + m_ * 16 + rl) * 32 + ko]; \
    _Pragma("unroll") for (int n_ = 0; n_ < 4; ++n_)                            \
        bb[n_] = *(const bf16x8*)&Bs[bufi][(wc * 64 + n_ * 16 + rl) * 32 + ko]; \
    _Pragma("unroll") for (int m_ = 0; m_ < 4; ++m_)                            \
        _Pragma("unroll") for (int n_ = 0; n_ < 4; ++n_)                        \
            acc[m_][n_] = __builtin_amdgcn_mfma_f32_16x16x32_bf16(              \
                af[m_], bb[n_], acc[m_][n_], 0, 0, 0);                          \
  }

  STAGE(0, 0);
  __syncthreads();
  int buf = 0;
  for (int kt = 32; kt < 1024; kt += 32) {
    STAGE(buf ^ 1, kt);
    COMPUTE(buf);
    __syncthreads();
    buf ^= 1;
  }
  COMPUTE(buf);

  // epilogue: C/D layout col=lane&15, row=(lane>>4)*4+j  [m89-verified]
#pragma unroll
  for (int m_ = 0; m_ < 4; ++m_) {
    int row = m0 + wr * 64 + m_ * 16 + ((lane >> 4) << 2);
#pragma unroll
    for (int n_ = 0; n_ < 4; ++n_) {
      int col = n0 + wc * 64 + n_ * 16 + (lane & 15);
      if constexpr (EPI == 0) {
        int src = (col & 1) ? 1024 + (col >> 1) : (col >> 1);
        float bv = bias[src];
#pragma unroll
        for (int j = 0; j < 4; ++j) {
          float v = acc[m_][n_][j] + bv;
          float g = __shfl_xor(v, 1);     // partner column (a<->gate)
          if (!(col & 1)) {
            float kv = v / (1.f + __expf(-g));
            ((bf16_t*)outp)[(size_t)(row + j) * 1024 + (col >> 1)] = (bf16_t)kv;
          }
        }
      } else {
        float bv = (col < 496) ? bias[col] : 0.f;
#pragma unroll
        for (int j = 0; j < 4; ++j)
          ((float*)outp)[(size_t)(row + j) * 512 + col] = acc[m_][n_][j] + bv;
      }
    }
  }
#undef STAGE
#undef COMPUTE
}

// ---------- softmax + depthwise dynamic conv + bias + residual ----------
// block: 64 tokens x 1 head; 256 threads (lane=d, tid>>6 = token quarter)
__global__ __launch_bounds__(256) void conv_kernel(const bf16_t* __restrict__ Kin,
                                                   const float* __restrict__ logits,
                                                   const float* __restrict__ x,
                                                   const float* __restrict__ conv_bias,
                                                   float* __restrict__ out) {
  __shared__ bf16_t ks[94][64];    // tokens t0-15 .. t0+78
  __shared__ float wls[64][32];    // softmaxed kernels
  int tid = threadIdx.x;
  int t0 = blockIdx.x * 64;
  int hh = blockIdx.y;
  int b = blockIdx.z;

  // stage k halo slice (zero outside [0,T))
  for (int i = tid; i < 94 * 8; i += 256) {
    int r = i >> 3;
    int seg = (i & 7) * 8;
    int t = t0 - 15 + r;
    bf16x8 v = {};
    if (t >= 0 && t < 2048)
      v = *(const bf16x8*)&Kin[((size_t)b * 2048 + t) * 1024 + hh * 64 + seg];
    *(bf16x8*)&ks[r][seg] = v;
  }
  // per-token softmax over K=31
  if (tid < 64) {
    int t = t0 + tid;
    const float* lp = logits + ((size_t)b * 2048 + t) * 512 + hh * 31;
    float l[31];
    float mx = -1e30f;
#pragma unroll
    for (int i = 0; i < 31; ++i) { l[i] = lp[i]; mx = fmaxf(mx, l[i]); }
    float ssum = 0.f;
#pragma unroll
    for (int i = 0; i < 31; ++i) { l[i] = __expf(l[i] - mx); ssum += l[i]; }
    float inv = 1.f / ssum;
#pragma unroll
    for (int i = 0; i < 31; ++i) wls[tid][i] = l[i] * inv;
  }
  __syncthreads();

  int lane = tid & 63;   // d within head
  int tq = tid >> 6;     // token quarter (16 tokens each)
  float win[46];
#pragma unroll
  for (int j = 0; j < 46; ++j) win[j] = (float)ks[tq * 16 + j][lane];
  float cb = conv_bias[hh * 64 + lane];
#pragma unroll
  for (int j = 0; j < 16; ++j) {
    int trow = tq * 16 + j;
    float wv[31];
#pragma unroll
    for (int i4 = 0; i4 < 7; ++i4) {
      f32x4 w4 = *(const f32x4*)&wls[trow][i4 * 4];
      wv[i4 * 4 + 0] = w4[0]; wv[i4 * 4 + 1] = w4[1];
      wv[i4 * 4 + 2] = w4[2]; wv[i4 * 4 + 3] = w4[3];
    }
    wv[28] = wls[trow][28]; wv[29] = wls[trow][29]; wv[30] = wls[trow][30];
    float a = 0.f;
#pragma unroll
    for (int i = 0; i < 31; ++i) a += wv[i] * win[j + i];
    size_t off = ((size_t)b * 2048 + t0 + trow) * 1024 + hh * 64 + lane;
    out[off] = a + cb + x[off];
  }
}

extern "C" void kernel_launch(void* const* d_in, const int* in_sizes, int n_in,
                              void* d_out, int out_size, void* d_ws, size_t ws_size,
                              hipStream_t stream) {
  const float* x         = (const float*)d_in[0];
  const float* Wk        = (const float*)d_in[1];
  const float* bk        = (const float*)d_in[2];
  const float* Wck       = (const float*)d_in[3];
  const float* bck       = (const float*)d_in[4];
  const float* gamma     = (const float*)d_in[5];
  const float* beta      = (const float*)d_in[6];
  const float* conv_bias = (const float*)d_in[7];
  float* out = (float*)d_out;

  char* ws = (char*)d_ws;
  bf16_t* h      = (bf16_t*)(ws);                  // 16384*1024*2 = 32MB
  bf16_t* kbuf   = (bf16_t*)(ws + (33554432));     // 32MB
  bf16_t* WT1    = (bf16_t*)(ws + (67108864));     // 2048*1024*2 = 4MB
  bf16_t* WT2    = (bf16_t*)(ws + (71303168));     // 512*1024*2 = 1MB
  float*  logits = (float*)(ws + (72351744));      // 16384*512*4 = 32MB

  prep_wk<<<2048, 256, 0, stream>>>(Wk, WT1);
  prep_wck<<<512, 256, 0, stream>>>(Wck, WT2);
  ln_kernel<<<16384, 256, 0, stream>>>(x, gamma, beta, h);
  gemm128<0><<<dim3(16, 128), 256, 0, stream>>>(h, WT1, bk, kbuf);
  gemm128<1><<<dim3(4, 128), 256, 0, stream>>>(kbuf, WT2, bck, logits);
  conv_kernel<<<dim3(32, 16, 8), 256, 0, stream>>>(kbuf, logits, x, conv_bias, out);
}

// Round 2
// 292.674 us; speedup vs baseline: 1.0382x; 1.0382x over previous
//
#include <hip/hip_runtime.h>

// DynamicConv: LN -> GEMM+GLU -> GEMM+softmax(K=31) -> depthwise dynamic conv + residual
// B=8, T=2048, C=1024, H=16, hd=64, K=31.
// GEMM1 (16384x2048x1024) now uses the 256^2 / BK=64 8-phase counted-vmcnt schedule.

typedef __bf16 bf16_t;
typedef __attribute__((ext_vector_type(8))) __bf16 bf16x8;
typedef __attribute__((ext_vector_type(4))) __bf16 bf16x4;
typedef __attribute__((ext_vector_type(4))) float f32x4;

__device__ __forceinline__ void gload_lds16(const void* g, void* l) {
  void* gg = const_cast<void*>(g);
  __builtin_amdgcn_global_load_lds(
      (__attribute__((address_space(1))) unsigned int*)gg,
      (__attribute__((address_space(3))) unsigned int*)l, 16, 0, 0);
}

// ---------- weight prep: transpose to [N][K] bf16 ----------
__global__ __launch_bounds__(256) void prep_wk(const float* __restrict__ Wk,
                                               bf16_t* __restrict__ WT) {
  int c = blockIdx.x;                       // [0,2048)
  int s = (c & 1) ? 1024 + (c >> 1) : (c >> 1);
  int k = threadIdx.x * 4;
  bf16x4 v;
#pragma unroll
  for (int j = 0; j < 4; ++j) v[j] = (bf16_t)Wk[(size_t)(k + j) * 2048 + s];
  *(bf16x4*)&WT[(size_t)c * 1024 + k] = v;
}

__global__ __launch_bounds__(256) void prep_wck(const float* __restrict__ Wck,
                                                bf16_t* __restrict__ WT) {
  int n = blockIdx.x;                       // [0,512)
  int k = threadIdx.x * 4;
  bf16x4 v;
#pragma unroll
  for (int j = 0; j < 4; ++j)
    v[j] = (n < 496) ? (bf16_t)Wck[(size_t)(k + j) * 496 + n] : (bf16_t)(0.f);
  *(bf16x4*)&WT[(size_t)n * 1024 + k] = v;
}

// ---------- layernorm: x[row][1024] -> h bf16 ----------
__global__ __launch_bounds__(256) void ln_kernel(const float* __restrict__ x,
                                                 const float* __restrict__ gamma,
                                                 const float* __restrict__ beta,
                                                 bf16_t* __restrict__ h) {
  int row = blockIdx.x;
  int tid = threadIdx.x;
  int lane = tid & 63, wid = tid >> 6;
  const float4* xr = (const float4*)(x + (size_t)row * 1024);
  float4 v = xr[tid];
  __shared__ float red[4];
  __shared__ float bc[2];
  float s = v.x + v.y + v.z + v.w;
#pragma unroll
  for (int off = 32; off > 0; off >>= 1) s += __shfl_down(s, off);
  if (lane == 0) red[wid] = s;
  __syncthreads();
  if (tid == 0) bc[0] = (red[0] + red[1] + red[2] + red[3]) * (1.f / 1024.f);
  __syncthreads();
  float mu = bc[0];
  float dx = v.x - mu, dy = v.y - mu, dz = v.z - mu, dw = v.w - mu;
  float s2 = dx * dx + dy * dy + dz * dz + dw * dw;
#pragma unroll
  for (int off = 32; off > 0; off >>= 1) s2 += __shfl_down(s2, off);
  if (lane == 0) red[wid] = s2;
  __syncthreads();
  if (tid == 0)
    bc[1] = rsqrtf((red[0] + red[1] + red[2] + red[3]) * (1.f / 1024.f) + 1e-5f);
  __syncthreads();
  float rs = bc[1];
  const float4* g4 = (const float4*)gamma;
  const float4* b4 = (const float4*)beta;
  float4 gv = g4[tid], bv = b4[tid];
  bf16x4 o;
  o[0] = (bf16_t)(dx * rs * gv.x + bv.x);
  o[1] = (bf16_t)(dy * rs * gv.y + bv.y);
  o[2] = (bf16_t)(dz * rs * gv.z + bv.z);
  o[3] = (bf16_t)(dw * rs * gv.w + bv.w);
  *(bf16x4*)&h[(size_t)row * 1024 + tid * 4] = o;
}

// ---------- GEMM1: 256x256 tile, BK=64, 8 waves, 8-phase counted-vmcnt ----------
// A = h [16384][1024], B = WT1 [2048][1024] (B^T layout), GLU epilogue -> kbuf bf16 [16384][1024].
// LDS (dynamic 128KB): A[2buf][2half][128][64] @0, B[2buf][2half][128][64] @65536.
// Swizzle: phys_colbyte = colbyte ^ ((row&7)<<4), applied on global SOURCE (stage) and ds_read.
__global__ __launch_bounds__(512, 2) void gemm256_glu(const bf16_t* __restrict__ Ag,
                                                      const bf16_t* __restrict__ Bg,
                                                      const float* __restrict__ bias,
                                                      bf16_t* __restrict__ outp) {
  extern __shared__ char smem[];
  const int tid = threadIdx.x;
  const int lane = tid & 63;
  const int wid = tid >> 6;
  const int wr = wid >> 2;   // 0..1  (M half)
  const int wc = wid & 3;    // 0..3  (N quarter)

  // XCD-aware bijective swizzle: 512 blocks, 8 XCDs, 64 contiguous per XCD.
  int bid = blockIdx.x;
  int swz = (bid & 7) * 64 + (bid >> 3);
  int m0 = (swz >> 3) * 256;
  int n0 = (swz & 7) * 256;

  // fragment-read addressing (byte offsets in smem)
  const int xr = (lane & 7) << 4;
  const int cs0 = (((lane >> 4) << 4) ^ xr);   // k-step 0 colbyte (swizzled)
  const int cs1 = cs0 ^ 64;                    // k-step 1
  const int aBase = wr * 16384 + (lane & 15) * 128;
  const int bBase = 65536 + (wc >> 1) * 16384 + (wc & 1) * 8192 + (lane & 15) * 128;

  // staging addressing (2 gload_lds per half-tile; linear LDS dest, swizzled global src)
  const int sidx0 = tid, sidx1 = tid + 512;
  const int srow0 = sidx0 >> 3, srow1 = sidx1 >> 3;
  const int scol0 = ((((sidx0 & 7) << 4) ^ ((srow0 & 7) << 4)) >> 1);
  const int scol1 = ((((sidx1 & 7) << 4) ^ ((srow1 & 7) << 4)) >> 1);
  const int d0 = sidx0 * 16, d1 = sidx1 * 16;

  f32x4 acc[8][4] = {};
  bf16x8 bq[4][2];

#define STAGE_A(buf, h_, kt)                                                          \
  {                                                                                   \
    gload_lds16(Ag + (size_t)(m0 + (h_)*128 + srow0) * 1024 + (kt) + scol0,           \
                smem + (buf)*32768 + (h_)*16384 + d0);                                \
    gload_lds16(Ag + (size_t)(m0 + (h_)*128 + srow1) * 1024 + (kt) + scol1,           \
                smem + (buf)*32768 + (h_)*16384 + d1);                                \
  }
#define STAGE_B(buf, h_, kt)                                                          \
  {                                                                                   \
    gload_lds16(Bg + (size_t)(n0 + (h_)*128 + srow0) * 1024 + (kt) + scol0,           \
                smem + 65536 + (buf)*32768 + (h_)*16384 + d0);                        \
    gload_lds16(Bg + (size_t)(n0 + (h_)*128 + srow1) * 1024 + (kt) + scol1,           \
                smem + 65536 + (buf)*32768 + (h_)*16384 + d1);                        \
  }
#define LDA(buf, f, s) (*(const bf16x8*)(smem + (buf)*32768 + aBase + (f)*2048 + ((s) ? cs1 : cs0)))
#define LDB(buf, g, s) (*(const bf16x8*)(smem + bBase + (buf)*32768 + (g)*2048 + ((s) ? cs1 : cs0)))
#define MFMA_(a, b, c) __builtin_amdgcn_mfma_f32_16x16x32_bf16(a, b, c, 0, 0, 0)

// One phase: 4 (or 12) ds_reads | 1 half-tile stage | barrier | 16 MFMA | [vmcnt] | barrier
#define PHASE(buf, f0, P0, STAGE_STMT, TAIL_VM)                                       \
  {                                                                                   \
    bf16x8 a00 = LDA(buf, f0, 0), a01 = LDA(buf, f0, 1);                              \
    bf16x8 a10 = LDA(buf, (f0) + 1, 0), a11 = LDA(buf, (f0) + 1, 1);                  \
    if (P0) {                                                                         \
      _Pragma("unroll") for (int g = 0; g < 4; ++g) {                                 \
        bq[g][0] = LDB(buf, g, 0);                                                    \
        bq[g][1] = LDB(buf, g, 1);                                                    \
      }                                                                               \
    }                                                                                 \
    STAGE_STMT;                                                                       \
    __builtin_amdgcn_s_barrier();                                                     \
    __builtin_amdgcn_s_setprio(1);                                                    \
    _Pragma("unroll") for (int g = 0; g < 4; ++g) {                                   \
      acc[f0][g] = MFMA_(a00, bq[g][0], acc[f0][g]);                                  \
      acc[f0][g] = MFMA_(a01, bq[g][1], acc[f0][g]);                                  \
      acc[(f0) + 1][g] = MFMA_(a10, bq[g][0], acc[(f0) + 1][g]);                      \
      acc[(f0) + 1][g] = MFMA_(a11, bq[g][1], acc[(f0) + 1][g]);                      \
    }                                                                                 \
    __builtin_amdgcn_s_setprio(0);                                                    \
    TAIL_VM;                                                                          \
    __builtin_amdgcn_s_barrier();                                                     \
  }

  // prologue: tile0 (B then A) + B of tile1; need tile0 landed -> vmcnt(4)
  STAGE_B(0, 0, 0); STAGE_B(0, 1, 0); STAGE_A(0, 0, 0); STAGE_A(0, 1, 0);
  STAGE_B(1, 0, 64); STAGE_B(1, 1, 64);
  asm volatile("s_waitcnt vmcnt(4)" ::: "memory");
  __builtin_amdgcn_s_barrier();

  // steady state: tiles 0..13.  Per tile: p0/p1 stage A[t+1] (other buf, freed),
  // p2/p3 stage B[t+2] (same buf; its B region was fully read at this tile's p0).
  // Boundary vmcnt(4): keep only B[t+2]'s 4 loads in flight; A[t+1],B[t+1] landed.
  for (int t = 0; t < 14; ++t) {
    const int buf = t & 1, nbuf = buf ^ 1;
    const int ktA = (t + 1) * 64, ktB = (t + 2) * 64;
    PHASE(buf, 0, 1, STAGE_A(nbuf, 0, ktA), ((void)0));
    PHASE(buf, 2, 0, STAGE_A(nbuf, 1, ktA), ((void)0));
    PHASE(buf, 4, 0, STAGE_B(buf, 0, ktB), ((void)0));
    PHASE(buf, 6, 0, STAGE_B(buf, 1, ktB),
          asm volatile("s_waitcnt vmcnt(4)" ::: "memory"));
  }
  // t=14: stage A[15] only; drain to 0 so tile15 is fully landed
  PHASE(0, 0, 1, STAGE_A(1, 0, 960), ((void)0));
  PHASE(0, 2, 0, STAGE_A(1, 1, 960), ((void)0));
  PHASE(0, 4, 0, ((void)0), ((void)0));
  PHASE(0, 6, 0, ((void)0), asm volatile("s_waitcnt vmcnt(0)" ::: "memory"));
  // t=15: compute only
  PHASE(1, 0, 1, ((void)0), ((void)0));
  PHASE(1, 2, 0, ((void)0), ((void)0));
  PHASE(1, 4, 0, ((void)0), ((void)0));
  PHASE(1, 6, 0, ((void)0), ((void)0));

  // GLU epilogue: C/D layout col=lane&15, row=(lane>>4)*4+j
#pragma unroll
  for (int f = 0; f < 8; ++f) {
    int row = m0 + wr * 128 + f * 16 + ((lane >> 4) << 2);
#pragma unroll
    for (int g = 0; g < 4; ++g) {
      int col = n0 + wc * 64 + g * 16 + (lane & 15);
      int src = (col & 1) ? 1024 + (col >> 1) : (col >> 1);
      float bv = bias[src];
#pragma unroll
      for (int j = 0; j < 4; ++j) {
        float v = acc[f][g][j] + bv;
        float gt = __shfl_xor(v, 1);   // partner column (a<->gate)
        if (!(col & 1)) {
          float kv = v / (1.f + __expf(-gt));
          outp[(size_t)(row + j) * 1024 + (col >> 1)] = (bf16_t)kv;
        }
      }
    }
  }
#undef STAGE_A
#undef STAGE_B
#undef LDA
#undef LDB
#undef MFMA_
#undef PHASE
}

// ---------- GEMM2: 128x128 tile (m97 structure), bias epilogue -> f32 logits ----------
__global__ __launch_bounds__(256, 2) void gemm128_bias(const bf16_t* __restrict__ Ag,
                                                       const bf16_t* __restrict__ Bg,
                                                       const float* __restrict__ bias,
                                                       float* __restrict__ outp) {
  __shared__ bf16_t As[2][128 * 32];
  __shared__ bf16_t Bs[2][128 * 32];
  int tid = threadIdx.x;
  int lane = tid & 63;
  int wid = tid >> 6;
  int wr = wid >> 1, wc = wid & 1;
  int n0 = blockIdx.x * 128;
  int m0 = blockIdx.y * 128;

  f32x4 acc[4][4] = {};

#define STAGE(bufi, kt)                                                         \
  {                                                                             \
    _Pragma("unroll") for (int s_ = 0; s_ < 2; ++s_) {                          \
      int idx = (tid + s_ * 256) * 8;                                           \
      int row = idx >> 5;                                                       \
      int col = idx & 31;                                                       \
      gload_lds16(Ag + (size_t)(m0 + row) * 1024 + (kt) + col, &As[bufi][idx]); \
      gload_lds16(Bg + (size_t)(n0 + row) * 1024 + (kt) + col, &Bs[bufi][idx]); \
    }                                                                           \
  }

#define COMPUTE(bufi)                                                           \
  {                                                                             \
    int ko = (lane >> 4) * 8;                                                   \
    int rl = lane & 15;                                                         \
    bf16x8 af[4], bb[4];                                                        \
    _Pragma("unroll") for (int m_ = 0; m_ < 4; ++m_)                            \
        af[m_] = *(const bf16x8*)&As[bufi][(wr * 64 + m_ * 16 + rl) * 32 + ko]; \
    _Pragma("unroll") for (int n_ = 0; n_ < 4; ++n_)                            \
        bb[n_] = *(const bf16x8*)&Bs[bufi][(wc * 64 + n_ * 16 + rl) * 32 + ko]; \
    _Pragma("unroll") for (int m_ = 0; m_ < 4; ++m_)                            \
        _Pragma("unroll") for (int n_ = 0; n_ < 4; ++n_)                        \
            acc[m_][n_] = __builtin_amdgcn_mfma_f32_16x16x32_bf16(              \
                af[m_], bb[n_], acc[m_][n_], 0, 0, 0);                          \
  }

  STAGE(0, 0);
  __syncthreads();
  int buf = 0;
  for (int kt = 32; kt < 1024; kt += 32) {
    STAGE(buf ^ 1, kt);
    COMPUTE(buf);
    __syncthreads();
    buf ^= 1;
  }
  COMPUTE(buf);

#pragma unroll
  for (int m_ = 0; m_ < 4; ++m_) {
    int row = m0 + wr * 64 + m_ * 16 + ((lane >> 4) << 2);
#pragma unroll
    for (int n_ = 0; n_ < 4; ++n_) {
      int col = n0 + wc * 64 + n_ * 16 + (lane & 15);
      float bv = (col < 496) ? bias[col] : 0.f;
#pragma unroll
      for (int j = 0; j < 4; ++j)
        outp[(size_t)(row + j) * 512 + col] = acc[m_][n_][j] + bv;
    }
  }
#undef STAGE
#undef COMPUTE
}

// ---------- softmax + depthwise dynamic conv + bias + residual ----------
__global__ __launch_bounds__(256) void conv_kernel(const bf16_t* __restrict__ Kin,
                                                   const float* __restrict__ logits,
                                                   const float* __restrict__ x,
                                                   const float* __restrict__ conv_bias,
                                                   float* __restrict__ out) {
  __shared__ bf16_t ks[94][64];
  __shared__ float wls[64][32];
  int tid = threadIdx.x;
  int t0 = blockIdx.x * 64;
  int hh = blockIdx.y;
  int b = blockIdx.z;

  for (int i = tid; i < 94 * 8; i += 256) {
    int r = i >> 3;
    int seg = (i & 7) * 8;
    int t = t0 - 15 + r;
    bf16x8 v = {};
    if (t >= 0 && t < 2048)
      v = *(const bf16x8*)&Kin[((size_t)b * 2048 + t) * 1024 + hh * 64 + seg];
    *(bf16x8*)&ks[r][seg] = v;
  }
  if (tid < 64) {
    int t = t0 + tid;
    const float* lp = logits + ((size_t)b * 2048 + t) * 512 + hh * 31;
    float l[31];
    float mx = -1e30f;
#pragma unroll
    for (int i = 0; i < 31; ++i) { l[i] = lp[i]; mx = fmaxf(mx, l[i]); }
    float ssum = 0.f;
#pragma unroll
    for (int i = 0; i < 31; ++i) { l[i] = __expf(l[i] - mx); ssum += l[i]; }
    float inv = 1.f / ssum;
#pragma unroll
    for (int i = 0; i < 31; ++i) wls[tid][i] = l[i] * inv;
  }
  __syncthreads();

  int lane = tid & 63;
  int tq = tid >> 6;
  float win[46];
#pragma unroll
  for (int j = 0; j < 46; ++j) win[j] = (float)ks[tq * 16 + j][lane];
  float cb = conv_bias[hh * 64 + lane];
#pragma unroll
  for (int j = 0; j < 16; ++j) {
    int trow = tq * 16 + j;
    float wv[31];
#pragma unroll
    for (int i4 = 0; i4 < 7; ++i4) {
      f32x4 w4 = *(const f32x4*)&wls[trow][i4 * 4];
      wv[i4 * 4 + 0] = w4[0]; wv[i4 * 4 + 1] = w4[1];
      wv[i4 * 4 + 2] = w4[2]; wv[i4 * 4 + 3] = w4[3];
    }
    wv[28] = wls[trow][28]; wv[29] = wls[trow][29]; wv[30] = wls[trow][30];
    float a = 0.f;
#pragma unroll
    for (int i = 0; i < 31; ++i) a += wv[i] * win[j + i];
    size_t off = ((size_t)b * 2048 + t0 + trow) * 1024 + hh * 64 + lane;
    out[off] = a + cb + x[off];
  }
}

extern "C" void kernel_launch(void* const* d_in, const int* in_sizes, int n_in,
                              void* d_out, int out_size, void* d_ws, size_t ws_size,
                              hipStream_t stream) {
  const float* x         = (const float*)d_in[0];
  const float* Wk        = (const float*)d_in[1];
  const float* bk        = (const float*)d_in[2];
  const float* Wck       = (const float*)d_in[3];
  const float* bck       = (const float*)d_in[4];
  const float* gamma     = (const float*)d_in[5];
  const float* beta      = (const float*)d_in[6];
  const float* conv_bias = (const float*)d_in[7];
  float* out = (float*)d_out;

  char* ws = (char*)d_ws;
  bf16_t* h      = (bf16_t*)(ws);                  // 32MB
  bf16_t* kbuf   = (bf16_t*)(ws + (33554432));     // 32MB
  bf16_t* WT1    = (bf16_t*)(ws + (67108864));     // 4MB
  bf16_t* WT2    = (bf16_t*)(ws + (71303168));     // 1MB
  float*  logits = (float*)(ws + (72351744));      // 32MB

  hipFuncSetAttribute((const void*)gemm256_glu,
                      hipFuncAttributeMaxDynamicSharedMemorySize, 131072);

  prep_wk<<<2048, 256, 0, stream>>>(Wk, WT1);
  prep_wck<<<512, 256, 0, stream>>>(Wck, WT2);
  ln_kernel<<<16384, 256, 0, stream>>>(x, gamma, beta, h);
  gemm256_glu<<<512, 512, 131072, stream>>>(h, WT1, bk, kbuf);
  gemm128_bias<<<dim3(4, 128), 256, 0, stream>>>(kbuf, WT2, bck, logits);
  conv_kernel<<<dim3(32, 16, 8), 256, 0, stream>>>(kbuf, logits, x, conv_bias, out);
}

// Round 3
// 290.565 us; speedup vs baseline: 1.0457x; 1.0073x over previous
//
#include <hip/hip_runtime.h>

// DynamicConv: LN -> GEMM+GLU -> GEMM+softmax(K=31) -> depthwise dynamic conv + residual
// B=8, T=2048, C=1024, H=16, hd=64, K=31.
// GEMM1: 256^2/BK=64, 4-barrier-per-tile schedule, reads issued in MFMA-tail region.

typedef __bf16 bf16_t;
typedef __attribute__((ext_vector_type(8))) __bf16 bf16x8;
typedef __attribute__((ext_vector_type(4))) __bf16 bf16x4;
typedef __attribute__((ext_vector_type(4))) float f32x4;

__device__ __forceinline__ void gload_lds16(const void* g, void* l) {
  void* gg = const_cast<void*>(g);
  __builtin_amdgcn_global_load_lds(
      (__attribute__((address_space(1))) unsigned int*)gg,
      (__attribute__((address_space(3))) unsigned int*)l, 16, 0, 0);
}

// ---------- weight prep: coalesced LDS-transpose to [N][K] bf16 ----------
// WT1[c][k] = Wk[k][src(c)], src interleaves a/gate columns (GLU pairs adjacent).
__global__ __launch_bounds__(256) void prep_wk(const float* __restrict__ Wk,
                                               bf16_t* __restrict__ WT) {
  __shared__ bf16_t T[64][66];
  int c0 = blockIdx.x * 64;   // 32 tiles over c
  int k0 = blockIdx.y * 64;   // 16 chunks over k
  int tid = threadIdx.x;
#pragma unroll
  for (int p = 0; p < 4; ++p) {
    int idx = p * 256 + tid;
    int r = idx >> 4;          // 0..63 (k row)
    int q = idx & 15;
    int strip = q >> 3;        // 0: a-cols, 1: gate-cols
    int col4 = (q & 7) * 4;    // 0..28
    const float* src = Wk + (size_t)(k0 + r) * 2048 + strip * 1024 + (c0 >> 1) + col4;
    float4 v = *(const float4*)src;
#pragma unroll
    for (int j = 0; j < 4; ++j) {
      int cl = (col4 + j) * 2 + strip;   // interleaved local c
      T[cl][r] = (bf16_t)((&v.x)[j]);
    }
  }
  __syncthreads();
  int c = tid >> 2;
  int kk = (tid & 3) * 16;
#pragma unroll
  for (int u = 0; u < 2; ++u) {
    bf16x8 o;
#pragma unroll
    for (int j = 0; j < 8; ++j) o[j] = T[c][kk + u * 8 + j];
    *(bf16x8*)&WT[(size_t)(c0 + c) * 1024 + k0 + kk + u * 8] = o;
  }
}

// WT2[n][k] = Wck[k][n] for n<496 else 0 (pad N to 512)
__global__ __launch_bounds__(256) void prep_wck(const float* __restrict__ Wck,
                                                bf16_t* __restrict__ WT) {
  __shared__ bf16_t T[64][66];
  int n0 = blockIdx.x * 64;   // 8 tiles over n
  int k0 = blockIdx.y * 64;   // 16 chunks over k
  int tid = threadIdx.x;
#pragma unroll
  for (int p = 0; p < 4; ++p) {
    int idx = p * 256 + tid;
    int r = idx >> 4;
    int q = idx & 15;
    int col = n0 + q * 4;
    float4 v = {0.f, 0.f, 0.f, 0.f};
    if (col < 496) v = *(const float4*)(Wck + (size_t)(k0 + r) * 496 + col);
#pragma unroll
    for (int j = 0; j < 4; ++j) T[q * 4 + j][r] = (bf16_t)((&v.x)[j]);
  }
  __syncthreads();
  int c = tid >> 2;
  int kk = (tid & 3) * 16;
#pragma unroll
  for (int u = 0; u < 2; ++u) {
    bf16x8 o;
#pragma unroll
    for (int j = 0; j < 8; ++j) o[j] = T[c][kk + u * 8 + j];
    *(bf16x8*)&WT[(size_t)(n0 + c) * 1024 + k0 + kk + u * 8] = o;
  }
}

// ---------- layernorm: x[row][1024] -> h bf16 ----------
__global__ __launch_bounds__(256) void ln_kernel(const float* __restrict__ x,
                                                 const float* __restrict__ gamma,
                                                 const float* __restrict__ beta,
                                                 bf16_t* __restrict__ h) {
  int row = blockIdx.x;
  int tid = threadIdx.x;
  int lane = tid & 63, wid = tid >> 6;
  const float4* xr = (const float4*)(x + (size_t)row * 1024);
  float4 v = xr[tid];
  __shared__ float red[4];
  __shared__ float bc[2];
  float s = v.x + v.y + v.z + v.w;
#pragma unroll
  for (int off = 32; off > 0; off >>= 1) s += __shfl_down(s, off);
  if (lane == 0) red[wid] = s;
  __syncthreads();
  if (tid == 0) bc[0] = (red[0] + red[1] + red[2] + red[3]) * (1.f / 1024.f);
  __syncthreads();
  float mu = bc[0];
  float dx = v.x - mu, dy = v.y - mu, dz = v.z - mu, dw = v.w - mu;
  float s2 = dx * dx + dy * dy + dz * dz + dw * dw;
#pragma unroll
  for (int off = 32; off > 0; off >>= 1) s2 += __shfl_down(s2, off);
  if (lane == 0) red[wid] = s2;
  __syncthreads();
  if (tid == 0)
    bc[1] = rsqrtf((red[0] + red[1] + red[2] + red[3]) * (1.f / 1024.f) + 1e-5f);
  __syncthreads();
  float rs = bc[1];
  const float4* g4 = (const float4*)gamma;
  const float4* b4 = (const float4*)beta;
  float4 gv = g4[tid], bv = b4[tid];
  bf16x4 o;
  o[0] = (bf16_t)(dx * rs * gv.x + bv.x);
  o[1] = (bf16_t)(dy * rs * gv.y + bv.y);
  o[2] = (bf16_t)(dz * rs * gv.z + bv.z);
  o[3] = (bf16_t)(dw * rs * gv.w + bv.w);
  *(bf16x4*)&h[(size_t)row * 1024 + tid * 4] = o;
}

// ---------- GEMM1: 256x256 tile, BK=64, 8 waves ----------
// Phase = [BAR; stages; lgkmcnt(0)+SB; setprio1; 16 MFMA; setprio0; reads-for-next].
// Reads issue in the MFMA-tail region (wave-skew overlap with other waves' MFMAs).
// bq (B frags) refilled at P3-end AFTER last use -> single set, no VGPR cliff.
// vmcnt derivation (steady, P3-top): outstanding = B[t+1]h1(2) + A[t+1](4) + B[t+2]h0(2);
// need first 6 landed -> vmcnt(2).  t=14: vmcnt(0) (full drain, no more stages).
__global__ __launch_bounds__(512, 2) void gemm256_glu(const bf16_t* __restrict__ Ag,
                                                      const bf16_t* __restrict__ Bg,
                                                      const float* __restrict__ bias,
                                                      bf16_t* __restrict__ outp) {
  extern __shared__ char smem[];
  const int tid = threadIdx.x;
  const int lane = tid & 63;
  const int wid = tid >> 6;
  const int wr = wid >> 2;   // 0..1  (M half)
  const int wc = wid & 3;    // 0..3  (N quarter)

  // XCD-aware bijective swizzle: 512 blocks, 8 XCDs, 64 contiguous per XCD.
  int bid = blockIdx.x;
  int swz = (bid & 7) * 64 + (bid >> 3);
  int m0 = (swz >> 3) * 256;
  int n0 = (swz & 7) * 256;

  // fragment-read addressing (byte offsets in smem); T2 swizzle byte^((row&7)<<4)
  const int xr = (lane & 7) << 4;
  const int cs0 = (((lane >> 4) << 4) ^ xr);
  const int cs1 = cs0 ^ 64;
  const int aBase = wr * 16384 + (lane & 15) * 128;
  const int bBase = 65536 + (wc >> 1) * 16384 + (wc & 1) * 8192 + (lane & 15) * 128;

  // staging addressing (2 gload_lds per half-tile; linear LDS dest, swizzled global src)
  const int sidx0 = tid, sidx1 = tid + 512;
  const int srow0 = sidx0 >> 3, srow1 = sidx1 >> 3;
  const int scol0 = ((((sidx0 & 7) << 4) ^ ((srow0 & 7) << 4)) >> 1);
  const int scol1 = ((((sidx1 & 7) << 4) ^ ((srow1 & 7) << 4)) >> 1);
  const int d0 = sidx0 * 16, d1 = sidx1 * 16;

  f32x4 acc[8][4] = {};
  bf16x8 bq[4][2], pc[2][2], pn[2][2];

#define STAGE_A(buf, h_, kt)                                                          \
  {                                                                                   \
    gload_lds16(Ag + (size_t)(m0 + (h_)*128 + srow0) * 1024 + (kt) + scol0,           \
                smem + (buf)*32768 + (h_)*16384 + d0);                                \
    gload_lds16(Ag + (size_t)(m0 + (h_)*128 + srow1) * 1024 + (kt) + scol1,           \
                smem + (buf)*32768 + (h_)*16384 + d1);                                \
  }
#define STAGE_B(buf, h_, kt)                                                          \
  {                                                                                   \
    gload_lds16(Bg + (size_t)(n0 + (h_)*128 + srow0) * 1024 + (kt) + scol0,           \
                smem + 65536 + (buf)*32768 + (h_)*16384 + d0);                        \
    gload_lds16(Bg + (size_t)(n0 + (h_)*128 + srow1) * 1024 + (kt) + scol1,           \
                smem + 65536 + (buf)*32768 + (h_)*16384 + d1);                        \
  }
#define LDA(buf, f, s) (*(const bf16x8*)(smem + (buf)*32768 + aBase + (f)*2048 + ((s) ? cs1 : cs0)))
#define LDB(buf, g, s) (*(const bf16x8*)(smem + bBase + (buf)*32768 + (g)*2048 + ((s) ? cs1 : cs0)))
#define MFMA_(a, b, c) __builtin_amdgcn_mfma_f32_16x16x32_bf16(a, b, c, 0, 0, 0)
#define RD_PAIR(D, buf, f)                                                            \
  { D[0][0] = LDA(buf, f, 0); D[0][1] = LDA(buf, f, 1);                               \
    D[1][0] = LDA(buf, (f) + 1, 0); D[1][1] = LDA(buf, (f) + 1, 1); }
#define RD_BQ(buf)                                                                    \
  { _Pragma("unroll") for (int g = 0; g < 4; ++g) {                                   \
      bq[g][0] = LDB(buf, g, 0); bq[g][1] = LDB(buf, g, 1); } }
#define MM_PAIR(F0, P)                                                                \
  { _Pragma("unroll") for (int g = 0; g < 4; ++g) {                                   \
      acc[F0][g]       = MFMA_(P[0][0], bq[g][0], acc[F0][g]);                        \
      acc[(F0) + 1][g] = MFMA_(P[1][0], bq[g][0], acc[(F0) + 1][g]);                  \
      acc[F0][g]       = MFMA_(P[0][1], bq[g][1], acc[F0][g]);                        \
      acc[(F0) + 1][g] = MFMA_(P[1][1], bq[g][1], acc[(F0) + 1][g]); } }
#define LGKM0                                                                         \
  asm volatile("s_waitcnt lgkmcnt(0)" ::: "memory");                                  \
  __builtin_amdgcn_sched_barrier(0)
#define BAR __builtin_amdgcn_s_barrier()
#define PRIO1 __builtin_amdgcn_s_setprio(1)
#define PRIO0 __builtin_amdgcn_s_setprio(0)

#define TILE(BUF, NBUF, T)                                                            \
  {                                                                                   \
    /* P0 */                                                                          \
    BAR;                                                                              \
    if ((T) < 15) { STAGE_A(NBUF, 0, ((T) + 1) * 64); STAGE_A(NBUF, 1, ((T) + 1) * 64); } \
    LGKM0; PRIO1; MM_PAIR(0, pc); PRIO0;                                              \
    RD_PAIR(pn, BUF, 2);                                                              \
    /* P1 */                                                                          \
    BAR;                                                                              \
    LGKM0; PRIO1; MM_PAIR(2, pn); PRIO0;                                              \
    RD_PAIR(pc, BUF, 4);                                                              \
    /* P2 */                                                                          \
    BAR;                                                                              \
    if ((T) < 14) STAGE_B(BUF, 0, ((T) + 2) * 64);                                    \
    LGKM0; PRIO1; MM_PAIR(4, pc); PRIO0;                                              \
    RD_PAIR(pn, BUF, 6);                                                              \
    /* P3 */                                                                          \
    if ((T) < 14)       { asm volatile("s_waitcnt vmcnt(2)" ::: "memory"); }          \
    else if ((T) == 14) { asm volatile("s_waitcnt vmcnt(0)" ::: "memory"); }          \
    BAR;                                                                              \
    if ((T) < 14) STAGE_B(BUF, 1, ((T) + 2) * 64);                                    \
    LGKM0; PRIO1; MM_PAIR(6, pn); PRIO0;                                              \
    if ((T) < 15) { RD_BQ(NBUF); RD_PAIR(pc, NBUF, 0); }                              \
  }

  // prologue: stage tile0 fully + tile1 B; wait tile0 (B1's 4 loads may pend)
  STAGE_B(0, 0, 0); STAGE_B(0, 1, 0); STAGE_A(0, 0, 0); STAGE_A(0, 1, 0);
  STAGE_B(1, 0, 64); STAGE_B(1, 1, 64);
  asm volatile("s_waitcnt vmcnt(4)" ::: "memory");
  BAR;
  RD_BQ(0); RD_PAIR(pc, 0, 0);

  for (int t = 0; t < 14; t += 2) {
    TILE(0, 1, t);
    TILE(1, 0, t + 1);
  }
  TILE(0, 1, 14);
  TILE(1, 0, 15);

  // GLU epilogue: C/D layout col=lane&15, row=(lane>>4)*4+j
#pragma unroll
  for (int f = 0; f < 8; ++f) {
    int row = m0 + wr * 128 + f * 16 + ((lane >> 4) << 2);
#pragma unroll
    for (int g = 0; g < 4; ++g) {
      int col = n0 + wc * 64 + g * 16 + (lane & 15);
      int src = (col & 1) ? 1024 + (col >> 1) : (col >> 1);
      float bv = bias[src];
#pragma unroll
      for (int j = 0; j < 4; ++j) {
        float v = acc[f][g][j] + bv;
        float gt = __shfl_xor(v, 1);   // partner column (a<->gate)
        if (!(col & 1)) {
          float kv = v / (1.f + __expf(-gt));
          outp[(size_t)(row + j) * 1024 + (col >> 1)] = (bf16_t)kv;
        }
      }
    }
  }
#undef STAGE_A
#undef STAGE_B
#undef LDA
#undef LDB
#undef MFMA_
#undef RD_PAIR
#undef RD_BQ
#undef MM_PAIR
#undef LGKM0
#undef BAR
#undef PRIO1
#undef PRIO0
#undef TILE
}

// ---------- GEMM2: 128x128 tile (m97 structure), bias epilogue -> f32 logits ----------
__global__ __launch_bounds__(256, 2) void gemm128_bias(const bf16_t* __restrict__ Ag,
                                                       const bf16_t* __restrict__ Bg,
                                                       const float* __restrict__ bias,
                                                       float* __restrict__ outp) {
  __shared__ bf16_t As[2][128 * 32];
  __shared__ bf16_t Bs[2][128 * 32];
  int tid = threadIdx.x;
  int lane = tid & 63;
  int wid = tid >> 6;
  int wr = wid >> 1, wc = wid & 1;
  int n0 = blockIdx.x * 128;
  int m0 = blockIdx.y * 128;

  f32x4 acc[4][4] = {};

#define STAGE(bufi, kt)                                                         \
  {                                                                             \
    _Pragma("unroll") for (int s_ = 0; s_ < 2; ++s_) {                          \
      int idx = (tid + s_ * 256) * 8;                                           \
      int row = idx >> 5;                                                       \
      int col = idx & 31;                                                       \
      gload_lds16(Ag + (size_t)(m0 + row) * 1024 + (kt) + col, &As[bufi][idx]); \
      gload_lds16(Bg + (size_t)(n0 + row) * 1024 + (kt) + col, &Bs[bufi][idx]); \
    }                                                                           \
  }

#define COMPUTE(bufi)                                                           \
  {                                                                             \
    int ko = (lane >> 4) * 8;                                                   \
    int rl = lane & 15;                                                         \
    bf16x8 af[4], bb[4];                                                        \
    _Pragma("unroll") for (int m_ = 0; m_ < 4; ++m_)                            \
        af[m_] = *(const bf16x8*)&As[bufi][(wr * 64 + m_ * 16 + rl) * 32 + ko]; \
    _Pragma("unroll") for (int n_ = 0; n_ < 4; ++n_)                            \
        bb[n_] = *(const bf16x8*)&Bs[bufi][(wc * 64 + n_ * 16 + rl) * 32 + ko]; \
    _Pragma("unroll") for (int m_ = 0; m_ < 4; ++m_)                            \
        _Pragma("unroll") for (int n_ = 0; n_ < 4; ++n_)                        \
            acc[m_][n_] = __builtin_amdgcn_mfma_f32_16x16x32_bf16(              \
                af[m_], bb[n_], acc[m_][n_], 0, 0, 0);                          \
  }

  STAGE(0, 0);
  __syncthreads();
  int buf = 0;
  for (int kt = 32; kt < 1024; kt += 32) {
    STAGE(buf ^ 1, kt);
    COMPUTE(buf);
    __syncthreads();
    buf ^= 1;
  }
  COMPUTE(buf);

#pragma unroll
  for (int m_ = 0; m_ < 4; ++m_) {
    int row = m0 + wr * 64 + m_ * 16 + ((lane >> 4) << 2);
#pragma unroll
    for (int n_ = 0; n_ < 4; ++n_) {
      int col = n0 + wc * 64 + n_ * 16 + (lane & 15);
      float bv = (col < 496) ? bias[col] : 0.f;
#pragma unroll
      for (int j = 0; j < 4; ++j)
        outp[(size_t)(row + j) * 512 + col] = acc[m_][n_][j] + bv;
    }
  }
#undef STAGE
#undef COMPUTE
}

// ---------- softmax + depthwise dynamic conv + bias + residual ----------
__global__ __launch_bounds__(256) void conv_kernel(const bf16_t* __restrict__ Kin,
                                                   const float* __restrict__ logits,
                                                   const float* __restrict__ x,
                                                   const float* __restrict__ conv_bias,
                                                   float* __restrict__ out) {
  __shared__ bf16_t ks[94][64];
  __shared__ float wls[64][32];
  int tid = threadIdx.x;
  int t0 = blockIdx.x * 64;
  int hh = blockIdx.y;
  int b = blockIdx.z;

  for (int i = tid; i < 94 * 8; i += 256) {
    int r = i >> 3;
    int seg = (i & 7) * 8;
    int t = t0 - 15 + r;
    bf16x8 v = {};
    if (t >= 0 && t < 2048)
      v = *(const bf16x8*)&Kin[((size_t)b * 2048 + t) * 1024 + hh * 64 + seg];
    *(bf16x8*)&ks[r][seg] = v;
  }
  if (tid < 64) {
    int t = t0 + tid;
    const float* lp = logits + ((size_t)b * 2048 + t) * 512 + hh * 31;
    float l[31];
    float mx = -1e30f;
#pragma unroll
    for (int i = 0; i < 31; ++i) { l[i] = lp[i]; mx = fmaxf(mx, l[i]); }
    float ssum = 0.f;
#pragma unroll
    for (int i = 0; i < 31; ++i) { l[i] = __expf(l[i] - mx); ssum += l[i]; }
    float inv = 1.f / ssum;
#pragma unroll
    for (int i = 0; i < 31; ++i) wls[tid][i] = l[i] * inv;
  }
  __syncthreads();

  int lane = tid & 63;
  int tq = tid >> 6;
  float win[46];
#pragma unroll
  for (int j = 0; j < 46; ++j) win[j] = (float)ks[tq * 16 + j][lane];
  float cb = conv_bias[hh * 64 + lane];
#pragma unroll
  for (int j = 0; j < 16; ++j) {
    int trow = tq * 16 + j;
    float wv[31];
#pragma unroll
    for (int i4 = 0; i4 < 7; ++i4) {
      f32x4 w4 = *(const f32x4*)&wls[trow][i4 * 4];
      wv[i4 * 4 + 0] = w4[0]; wv[i4 * 4 + 1] = w4[1];
      wv[i4 * 4 + 2] = w4[2]; wv[i4 * 4 + 3] = w4[3];
    }
    wv[28] = wls[trow][28]; wv[29] = wls[trow][29]; wv[30] = wls[trow][30];
    float a = 0.f;
#pragma unroll
    for (int i = 0; i < 31; ++i) a += wv[i] * win[j + i];
    size_t off = ((size_t)b * 2048 + t0 + trow) * 1024 + hh * 64 + lane;
    out[off] = a + cb + x[off];
  }
}

extern "C" void kernel_launch(void* const* d_in, const int* in_sizes, int n_in,
                              void* d_out, int out_size, void* d_ws, size_t ws_size,
                              hipStream_t stream) {
  const float* x         = (const float*)d_in[0];
  const float* Wk        = (const float*)d_in[1];
  const float* bk        = (const float*)d_in[2];
  const float* Wck       = (const float*)d_in[3];
  const float* bck       = (const float*)d_in[4];
  const float* gamma     = (const float*)d_in[5];
  const float* beta      = (const float*)d_in[6];
  const float* conv_bias = (const float*)d_in[7];
  float* out = (float*)d_out;

  char* ws = (char*)d_ws;
  bf16_t* h      = (bf16_t*)(ws);                  // 32MB
  bf16_t* kbuf   = (bf16_t*)(ws + (33554432));     // 32MB
  bf16_t* WT1    = (bf16_t*)(ws + (67108864));     // 4MB
  bf16_t* WT2    = (bf16_t*)(ws + (71303168));     // 1MB
  float*  logits = (float*)(ws + (72351744));      // 32MB

  hipFuncSetAttribute((const void*)gemm256_glu,
                      hipFuncAttributeMaxDynamicSharedMemorySize, 131072);

  prep_wk<<<dim3(32, 16), 256, 0, stream>>>(Wk, WT1);
  prep_wck<<<dim3(8, 16), 256, 0, stream>>>(Wck, WT2);
  ln_kernel<<<16384, 256, 0, stream>>>(x, gamma, beta, h);
  gemm256_glu<<<512, 512, 131072, stream>>>(h, WT1, bk, kbuf);
  gemm128_bias<<<dim3(4, 128), 256, 0, stream>>>(kbuf, WT2, bck, logits);
  conv_kernel<<<dim3(32, 16, 8), 256, 0, stream>>>(kbuf, logits, x, conv_bias, out);
}

// Round 4
// 285.411 us; speedup vs baseline: 1.0646x; 1.0181x over previous
//
#include <hip/hip_runtime.h>

// DynamicConv: LN -> GEMM+GLU -> GEMM+softmax(K=31) -> depthwise dynamic conv + residual
// B=8, T=2048, C=1024, H=16, hd=64, K=31.
// GEMM1: 256^2/BK=64, 8-wave, 4-phase/tile; MFMA ordered for dep-distance 8.

typedef __bf16 bf16_t;
typedef __attribute__((ext_vector_type(8))) __bf16 bf16x8;
typedef __attribute__((ext_vector_type(4))) __bf16 bf16x4;
typedef __attribute__((ext_vector_type(4))) float f32x4;

__device__ __forceinline__ void gload_lds16(const void* g, void* l) {
  void* gg = const_cast<void*>(g);
  __builtin_amdgcn_global_load_lds(
      (__attribute__((address_space(1))) unsigned int*)gg,
      (__attribute__((address_space(3))) unsigned int*)l, 16, 0, 0);
}

// ---------- weight prep: coalesced LDS-transpose to [N][K] bf16 ----------
__global__ __launch_bounds__(256) void prep_wk(const float* __restrict__ Wk,
                                               bf16_t* __restrict__ WT) {
  __shared__ bf16_t T[64][66];
  int c0 = blockIdx.x * 64;
  int k0 = blockIdx.y * 64;
  int tid = threadIdx.x;
#pragma unroll
  for (int p = 0; p < 4; ++p) {
    int idx = p * 256 + tid;
    int r = idx >> 4;
    int q = idx & 15;
    int strip = q >> 3;
    int col4 = (q & 7) * 4;
    const float* src = Wk + (size_t)(k0 + r) * 2048 + strip * 1024 + (c0 >> 1) + col4;
    float4 v = *(const float4*)src;
#pragma unroll
    for (int j = 0; j < 4; ++j) {
      int cl = (col4 + j) * 2 + strip;
      T[cl][r] = (bf16_t)((&v.x)[j]);
    }
  }
  __syncthreads();
  int c = tid >> 2;
  int kk = (tid & 3) * 16;
#pragma unroll
  for (int u = 0; u < 2; ++u) {
    bf16x8 o;
#pragma unroll
    for (int j = 0; j < 8; ++j) o[j] = T[c][kk + u * 8 + j];
    *(bf16x8*)&WT[(size_t)(c0 + c) * 1024 + k0 + kk + u * 8] = o;
  }
}

__global__ __launch_bounds__(256) void prep_wck(const float* __restrict__ Wck,
                                                bf16_t* __restrict__ WT) {
  __shared__ bf16_t T[64][66];
  int n0 = blockIdx.x * 64;
  int k0 = blockIdx.y * 64;
  int tid = threadIdx.x;
#pragma unroll
  for (int p = 0; p < 4; ++p) {
    int idx = p * 256 + tid;
    int r = idx >> 4;
    int q = idx & 15;
    int col = n0 + q * 4;
    float4 v = {0.f, 0.f, 0.f, 0.f};
    if (col < 496) v = *(const float4*)(Wck + (size_t)(k0 + r) * 496 + col);
#pragma unroll
    for (int j = 0; j < 4; ++j) T[q * 4 + j][r] = (bf16_t)((&v.x)[j]);
  }
  __syncthreads();
  int c = tid >> 2;
  int kk = (tid & 3) * 16;
#pragma unroll
  for (int u = 0; u < 2; ++u) {
    bf16x8 o;
#pragma unroll
    for (int j = 0; j < 8; ++j) o[j] = T[c][kk + u * 8 + j];
    *(bf16x8*)&WT[(size_t)(n0 + c) * 1024 + k0 + kk + u * 8] = o;
  }
}

// ---------- layernorm: x[row][1024] -> h bf16 ----------
__global__ __launch_bounds__(256) void ln_kernel(const float* __restrict__ x,
                                                 const float* __restrict__ gamma,
                                                 const float* __restrict__ beta,
                                                 bf16_t* __restrict__ h) {
  int row = blockIdx.x;
  int tid = threadIdx.x;
  int lane = tid & 63, wid = tid >> 6;
  const float4* xr = (const float4*)(x + (size_t)row * 1024);
  float4 v = xr[tid];
  __shared__ float red[4];
  __shared__ float bc[2];
  float s = v.x + v.y + v.z + v.w;
#pragma unroll
  for (int off = 32; off > 0; off >>= 1) s += __shfl_down(s, off);
  if (lane == 0) red[wid] = s;
  __syncthreads();
  if (tid == 0) bc[0] = (red[0] + red[1] + red[2] + red[3]) * (1.f / 1024.f);
  __syncthreads();
  float mu = bc[0];
  float dx = v.x - mu, dy = v.y - mu, dz = v.z - mu, dw = v.w - mu;
  float s2 = dx * dx + dy * dy + dz * dz + dw * dw;
#pragma unroll
  for (int off = 32; off > 0; off >>= 1) s2 += __shfl_down(s2, off);
  if (lane == 0) red[wid] = s2;
  __syncthreads();
  if (tid == 0)
    bc[1] = rsqrtf((red[0] + red[1] + red[2] + red[3]) * (1.f / 1024.f) + 1e-5f);
  __syncthreads();
  float rs = bc[1];
  const float4* g4 = (const float4*)gamma;
  const float4* b4 = (const float4*)beta;
  float4 gv = g4[tid], bv = b4[tid];
  bf16x4 o;
  o[0] = (bf16_t)(dx * rs * gv.x + bv.x);
  o[1] = (bf16_t)(dy * rs * gv.y + bv.y);
  o[2] = (bf16_t)(dz * rs * gv.z + bv.z);
  o[3] = (bf16_t)(dw * rs * gv.w + bv.w);
  *(bf16x4*)&h[(size_t)row * 1024 + tid * 4] = o;
}

// ---------- GEMM1: 256x256 tile, BK=64, 8 waves ----------
// MM_PAIR order: k-step OUTER -> each acc register reused at distance 8
// (>= MFMA result latency), keeping the matrix pipe fed.
__global__ __launch_bounds__(512, 2) void gemm256_glu(const bf16_t* __restrict__ Ag,
                                                      const bf16_t* __restrict__ Bg,
                                                      const float* __restrict__ bias,
                                                      bf16_t* __restrict__ outp) {
  extern __shared__ char smem[];
  const int tid = threadIdx.x;
  const int lane = tid & 63;
  const int wid = tid >> 6;
  const int wr = wid >> 2;
  const int wc = wid & 3;

  int bid = blockIdx.x;
  int swz = (bid & 7) * 64 + (bid >> 3);
  int m0 = (swz >> 3) * 256;
  int n0 = (swz & 7) * 256;

  const int xr = (lane & 7) << 4;
  const int cs0 = (((lane >> 4) << 4) ^ xr);
  const int cs1 = cs0 ^ 64;
  const int aBase = wr * 16384 + (lane & 15) * 128;
  const int bBase = 65536 + (wc >> 1) * 16384 + (wc & 1) * 8192 + (lane & 15) * 128;

  const int sidx0 = tid, sidx1 = tid + 512;
  const int srow0 = sidx0 >> 3, srow1 = sidx1 >> 3;
  const int scol0 = ((((sidx0 & 7) << 4) ^ ((srow0 & 7) << 4)) >> 1);
  const int scol1 = ((((sidx1 & 7) << 4) ^ ((srow1 & 7) << 4)) >> 1);
  const int d0 = sidx0 * 16, d1 = sidx1 * 16;

  f32x4 acc[8][4] = {};
  bf16x8 bq[4][2], pc[2][2], pn[2][2];

#define STAGE_A(buf, h_, kt)                                                          \
  {                                                                                   \
    gload_lds16(Ag + (size_t)(m0 + (h_)*128 + srow0) * 1024 + (kt) + scol0,           \
                smem + (buf)*32768 + (h_)*16384 + d0);                                \
    gload_lds16(Ag + (size_t)(m0 + (h_)*128 + srow1) * 1024 + (kt) + scol1,           \
                smem + (buf)*32768 + (h_)*16384 + d1);                                \
  }
#define STAGE_B(buf, h_, kt)                                                          \
  {                                                                                   \
    gload_lds16(Bg + (size_t)(n0 + (h_)*128 + srow0) * 1024 + (kt) + scol0,           \
                smem + 65536 + (buf)*32768 + (h_)*16384 + d0);                        \
    gload_lds16(Bg + (size_t)(n0 + (h_)*128 + srow1) * 1024 + (kt) + scol1,           \
                smem + 65536 + (buf)*32768 + (h_)*16384 + d1);                        \
  }
#define LDA(buf, f, s) (*(const bf16x8*)(smem + (buf)*32768 + aBase + (f)*2048 + ((s) ? cs1 : cs0)))
#define LDB(buf, g, s) (*(const bf16x8*)(smem + bBase + (buf)*32768 + (g)*2048 + ((s) ? cs1 : cs0)))
#define MFMA_(a, b, c) __builtin_amdgcn_mfma_f32_16x16x32_bf16(a, b, c, 0, 0, 0)
#define RD_PAIR(D, buf, f)                                                            \
  { D[0][0] = LDA(buf, f, 0); D[0][1] = LDA(buf, f, 1);                               \
    D[1][0] = LDA(buf, (f) + 1, 0); D[1][1] = LDA(buf, (f) + 1, 1); }
#define RD_BQ(buf)                                                                    \
  { _Pragma("unroll") for (int g = 0; g < 4; ++g) {                                   \
      bq[g][0] = LDB(buf, g, 0); bq[g][1] = LDB(buf, g, 1); } }
#define MM_PAIR(F0, P)                                                                \
  { _Pragma("unroll") for (int s = 0; s < 2; ++s) {                                   \
      _Pragma("unroll") for (int g = 0; g < 4; ++g) {                                 \
        acc[F0][g]       = MFMA_(P[0][s], bq[g][s], acc[F0][g]);                      \
        acc[(F0) + 1][g] = MFMA_(P[1][s], bq[g][s], acc[(F0) + 1][g]); } } }
#define LGKM0                                                                         \
  asm volatile("s_waitcnt lgkmcnt(0)" ::: "memory");                                  \
  __builtin_amdgcn_sched_barrier(0)
#define BAR __builtin_amdgcn_s_barrier()
#define PRIO1 __builtin_amdgcn_s_setprio(1)
#define PRIO0 __builtin_amdgcn_s_setprio(0)

#define TILE(BUF, NBUF, T)                                                            \
  {                                                                                   \
    /* P0 */                                                                          \
    BAR;                                                                              \
    if ((T) < 15) { STAGE_A(NBUF, 0, ((T) + 1) * 64); STAGE_A(NBUF, 1, ((T) + 1) * 64); } \
    LGKM0; PRIO1; MM_PAIR(0, pc); PRIO0;                                              \
    RD_PAIR(pn, BUF, 2);                                                              \
    /* P1 */                                                                          \
    BAR;                                                                              \
    LGKM0; PRIO1; MM_PAIR(2, pn); PRIO0;                                              \
    RD_PAIR(pc, BUF, 4);                                                              \
    /* P2 */                                                                          \
    BAR;                                                                              \
    if ((T) < 14) STAGE_B(BUF, 0, ((T) + 2) * 64);                                    \
    LGKM0; PRIO1; MM_PAIR(4, pc); PRIO0;                                              \
    RD_PAIR(pn, BUF, 6);                                                              \
    /* P3 */                                                                          \
    if ((T) < 14)       { asm volatile("s_waitcnt vmcnt(2)" ::: "memory"); }          \
    else if ((T) == 14) { asm volatile("s_waitcnt vmcnt(0)" ::: "memory"); }          \
    BAR;                                                                              \
    if ((T) < 14) STAGE_B(BUF, 1, ((T) + 2) * 64);                                    \
    LGKM0; PRIO1; MM_PAIR(6, pn); PRIO0;                                              \
    if ((T) < 15) { RD_BQ(NBUF); RD_PAIR(pc, NBUF, 0); }                              \
  }

  STAGE_B(0, 0, 0); STAGE_B(0, 1, 0); STAGE_A(0, 0, 0); STAGE_A(0, 1, 0);
  STAGE_B(1, 0, 64); STAGE_B(1, 1, 64);
  asm volatile("s_waitcnt vmcnt(4)" ::: "memory");
  BAR;
  RD_BQ(0); RD_PAIR(pc, 0, 0);

  for (int t = 0; t < 14; t += 2) {
    TILE(0, 1, t);
    TILE(1, 0, t + 1);
  }
  TILE(0, 1, 14);
  TILE(1, 0, 15);

  // GLU epilogue: C/D layout col=lane&15, row=(lane>>4)*4+j
#pragma unroll
  for (int f = 0; f < 8; ++f) {
    int row = m0 + wr * 128 + f * 16 + ((lane >> 4) << 2);
#pragma unroll
    for (int g = 0; g < 4; ++g) {
      int col = n0 + wc * 64 + g * 16 + (lane & 15);
      int src = (col & 1) ? 1024 + (col >> 1) : (col >> 1);
      float bv = bias[src];
#pragma unroll
      for (int j = 0; j < 4; ++j) {
        float v = acc[f][g][j] + bv;
        float gt = __shfl_xor(v, 1);
        if (!(col & 1)) {
          float kv = v / (1.f + __expf(-gt));
          outp[(size_t)(row + j) * 1024 + (col >> 1)] = (bf16_t)kv;
        }
      }
    }
  }
#undef STAGE_A
#undef STAGE_B
#undef LDA
#undef LDB
#undef MFMA_
#undef RD_PAIR
#undef RD_BQ
#undef MM_PAIR
#undef LGKM0
#undef BAR
#undef PRIO1
#undef PRIO0
#undef TILE
}

// ---------- GEMM2: 128x128 tile (m97 structure), bias epilogue -> f32 logits ----------
__global__ __launch_bounds__(256, 2) void gemm128_bias(const bf16_t* __restrict__ Ag,
                                                       const bf16_t* __restrict__ Bg,
                                                       const float* __restrict__ bias,
                                                       float* __restrict__ outp) {
  __shared__ bf16_t As[2][128 * 32];
  __shared__ bf16_t Bs[2][128 * 32];
  int tid = threadIdx.x;
  int lane = tid & 63;
  int wid = tid >> 6;
  int wr = wid >> 1, wc = wid & 1;
  int n0 = blockIdx.x * 128;
  int m0 = blockIdx.y * 128;

  f32x4 acc[4][4] = {};

#define STAGE(bufi, kt)                                                         \
  {                                                                             \
    _Pragma("unroll") for (int s_ = 0; s_ < 2; ++s_) {                          \
      int idx = (tid + s_ * 256) * 8;                                           \
      int row = idx >> 5;                                                       \
      int col = idx & 31;                                                       \
      gload_lds16(Ag + (size_t)(m0 + row) * 1024 + (kt) + col, &As[bufi][idx]); \
      gload_lds16(Bg + (size_t)(n0 + row) * 1024 + (kt) + col, &Bs[bufi][idx]); \
    }                                                                           \
  }

#define COMPUTE(bufi)                                                           \
  {                                                                             \
    int ko = (lane >> 4) * 8;                                                   \
    int rl = lane & 15;                                                         \
    bf16x8 af[4], bb[4];                                                        \
    _Pragma("unroll") for (int m_ = 0; m_ < 4; ++m_)                            \
        af[m_] = *(const bf16x8*)&As[bufi][(wr * 64 + m_ * 16 + rl) * 32 + ko]; \
    _Pragma("unroll") for (int n_ = 0; n_ < 4; ++n_)                            \
        bb[n_] = *(const bf16x8*)&Bs[bufi][(wc * 64 + n_ * 16 + rl) * 32 + ko]; \
    _Pragma("unroll") for (int m_ = 0; m_ < 4; ++m_)                            \
        _Pragma("unroll") for (int n_ = 0; n_ < 4; ++n_)                        \
            acc[m_][n_] = __builtin_amdgcn_mfma_f32_16x16x32_bf16(              \
                af[m_], bb[n_], acc[m_][n_], 0, 0, 0);                          \
  }

  STAGE(0, 0);
  __syncthreads();
  int buf = 0;
  for (int kt = 32; kt < 1024; kt += 32) {
    STAGE(buf ^ 1, kt);
    COMPUTE(buf);
    __syncthreads();
    buf ^= 1;
  }
  COMPUTE(buf);

#pragma unroll
  for (int m_ = 0; m_ < 4; ++m_) {
    int row = m0 + wr * 64 + m_ * 16 + ((lane >> 4) << 2);
#pragma unroll
    for (int n_ = 0; n_ < 4; ++n_) {
      int col = n0 + wc * 64 + n_ * 16 + (lane & 15);
      float bv = (col < 496) ? bias[col] : 0.f;
#pragma unroll
      for (int j = 0; j < 4; ++j)
        outp[(size_t)(row + j) * 512 + col] = acc[m_][n_][j] + bv;
    }
  }
#undef STAGE
#undef COMPUTE
}

// ---------- softmax + depthwise dynamic conv + bias + residual ----------
// softmax: 4 lanes per token, 8 logits each; 4-lane shfl_xor reduce (all 256 threads busy)
__global__ __launch_bounds__(256) void conv_kernel(const bf16_t* __restrict__ Kin,
                                                   const float* __restrict__ logits,
                                                   const float* __restrict__ x,
                                                   const float* __restrict__ conv_bias,
                                                   float* __restrict__ out) {
  __shared__ bf16_t ks[94][64];
  __shared__ float wls[64][32];
  int tid = threadIdx.x;
  int t0 = blockIdx.x * 64;
  int hh = blockIdx.y;
  int b = blockIdx.z;

  for (int i = tid; i < 94 * 8; i += 256) {
    int r = i >> 3;
    int seg = (i & 7) * 8;
    int t = t0 - 15 + r;
    bf16x8 v = {};
    if (t >= 0 && t < 2048)
      v = *(const bf16x8*)&Kin[((size_t)b * 2048 + t) * 1024 + hh * 64 + seg];
    *(bf16x8*)&ks[r][seg] = v;
  }
  {
    int tok = tid >> 2, part = tid & 3;
    const float* lp = logits + ((size_t)b * 2048 + t0 + tok) * 512 + hh * 31 + part * 8;
    float l[8];
#pragma unroll
    for (int j = 0; j < 8; ++j) l[j] = lp[j];
    if (part == 3) l[7] = -1e30f;   // mask element 31 (next head / pad)
    float mx = l[0];
#pragma unroll
    for (int j = 1; j < 8; ++j) mx = fmaxf(mx, l[j]);
    mx = fmaxf(mx, __shfl_xor(mx, 1));
    mx = fmaxf(mx, __shfl_xor(mx, 2));
    float ssum = 0.f;
#pragma unroll
    for (int j = 0; j < 8; ++j) l[j] = __expf(l[j] - mx);
    if (part == 3) l[7] = 0.f;
#pragma unroll
    for (int j = 0; j < 8; ++j) ssum += l[j];
    ssum += __shfl_xor(ssum, 1);
    ssum += __shfl_xor(ssum, 2);
    float inv = 1.f / ssum;
    f32x4 w0 = {l[0] * inv, l[1] * inv, l[2] * inv, l[3] * inv};
    f32x4 w1 = {l[4] * inv, l[5] * inv, l[6] * inv, l[7] * inv};
    *(f32x4*)&wls[tok][part * 8] = w0;
    *(f32x4*)&wls[tok][part * 8 + 4] = w1;
  }
  __syncthreads();

  int lane = tid & 63;
  int tq = tid >> 6;
  float win[46];
#pragma unroll
  for (int j = 0; j < 46; ++j) win[j] = (float)ks[tq * 16 + j][lane];
  float cb = conv_bias[hh * 64 + lane];
#pragma unroll
  for (int j = 0; j < 16; ++j) {
    int trow = tq * 16 + j;
    float wv[31];
#pragma unroll
    for (int i4 = 0; i4 < 7; ++i4) {
      f32x4 w4 = *(const f32x4*)&wls[trow][i4 * 4];
      wv[i4 * 4 + 0] = w4[0]; wv[i4 * 4 + 1] = w4[1];
      wv[i4 * 4 + 2] = w4[2]; wv[i4 * 4 + 3] = w4[3];
    }
    wv[28] = wls[trow][28]; wv[29] = wls[trow][29]; wv[30] = wls[trow][30];
    float a = 0.f;
#pragma unroll
    for (int i = 0; i < 31; ++i) a += wv[i] * win[j + i];
    size_t off = ((size_t)b * 2048 + t0 + trow) * 1024 + hh * 64 + lane;
    out[off] = a + cb + x[off];
  }
}

extern "C" void kernel_launch(void* const* d_in, const int* in_sizes, int n_in,
                              void* d_out, int out_size, void* d_ws, size_t ws_size,
                              hipStream_t stream) {
  const float* x         = (const float*)d_in[0];
  const float* Wk        = (const float*)d_in[1];
  const float* bk        = (const float*)d_in[2];
  const float* Wck       = (const float*)d_in[3];
  const float* bck       = (const float*)d_in[4];
  const float* gamma     = (const float*)d_in[5];
  const float* beta      = (const float*)d_in[6];
  const float* conv_bias = (const float*)d_in[7];
  float* out = (float*)d_out;

  char* ws = (char*)d_ws;
  bf16_t* h      = (bf16_t*)(ws);                  // 32MB
  bf16_t* kbuf   = (bf16_t*)(ws + (33554432));     // 32MB
  bf16_t* WT1    = (bf16_t*)(ws + (67108864));     // 4MB
  bf16_t* WT2    = (bf16_t*)(ws + (71303168));     // 1MB
  float*  logits = (float*)(ws + (72351744));      // 32MB

  hipFuncSetAttribute((const void*)gemm256_glu,
                      hipFuncAttributeMaxDynamicSharedMemorySize, 131072);

  prep_wk<<<dim3(32, 16), 256, 0, stream>>>(Wk, WT1);
  prep_wck<<<dim3(8, 16), 256, 0, stream>>>(Wck, WT2);
  ln_kernel<<<16384, 256, 0, stream>>>(x, gamma, beta, h);
  gemm256_glu<<<512, 512, 131072, stream>>>(h, WT1, bk, kbuf);
  gemm128_bias<<<dim3(4, 128), 256, 0, stream>>>(kbuf, WT2, bck, logits);
  conv_kernel<<<dim3(32, 16, 8), 256, 0, stream>>>(kbuf, logits, x, conv_bias, out);
}